// Round 1
// 355.500 us; speedup vs baseline: 1.3028x; 1.3028x over previous
//
#include <hip/hip_runtime.h>

typedef float fx4 __attribute__((ext_vector_type(4)));
typedef __bf16 bf16x8 __attribute__((ext_vector_type(8)));
typedef unsigned short ushort8 __attribute__((ext_vector_type(8)));
typedef unsigned int uint2v __attribute__((ext_vector_type(2)));
typedef unsigned int uint4v __attribute__((ext_vector_type(4)));

#define MFMA16(a, b, c) __builtin_amdgcn_mfma_f32_16x16x32_bf16((a), (b), (c), 0, 0, 0)

__device__ __forceinline__ unsigned short f2bf(float f) {
  unsigned int u = __float_as_uint(f);
  return (unsigned short)((u + 0x7FFFu + ((u >> 16) & 1u)) >> 16);
}

__device__ __forceinline__ ushort8 pack8(fx4 a, fx4 b) {
  ushort8 v;
  v[0] = f2bf(a[0]); v[1] = f2bf(a[1]); v[2] = f2bf(a[2]); v[3] = f2bf(a[3]);
  v[4] = f2bf(b[0]); v[5] = f2bf(b[1]); v[6] = f2bf(b[2]); v[7] = f2bf(b[3]);
  return v;
}

__device__ __forceinline__ uint2v pack2(fx4 v) {
  uint2v r;
  r[0] = (unsigned int)f2bf(v[0]) | ((unsigned int)f2bf(v[1]) << 16);
  r[1] = (unsigned int)f2bf(v[2]) | ((unsigned int)f2bf(v[3]) << 16);
  return r;
}

// C-layout (col=x on l16, row=y on quad*4+r, two 16-row source tiles A,B) ->
// B-fragment (lane l16 = x, k-dim = y). Same quad-redistribute as the verified
// P->PV path in the old k_attn.
__device__ __forceinline__ bf16x8 xfrm(uint2v A, uint2v B, int quad, int src0, int src1) {
  uint4v pf;
#pragma unroll
  for (int d = 0; d < 2; d++) {
    int a0 = __shfl((int)A[d], src0, 64);
    int b0 = __shfl((int)B[d], src0, 64);
    pf[d] = (unsigned int)((quad < 2) ? a0 : b0);
    int a1 = __shfl((int)A[d], src1, 64);
    int b1 = __shfl((int)B[d], src1, 64);
    pf[2 + d] = (unsigned int)((quad < 2) ? a1 : b1);
  }
  return __builtin_bit_cast(bf16x8, pf);
}

// async global->LDS, 16B per lane; LDS dest is wave-uniform base, lane i lands at +16*i
__device__ __forceinline__ void gl2lds16(const unsigned short* g, void* lds_base) {
  __builtin_amdgcn_global_load_lds(
      (const __attribute__((address_space(1))) void*)(unsigned long long)(g),
      (__attribute__((address_space(3))) void*)(unsigned int)(unsigned long long)(lds_base),
      16, 0, 0);
}

// ---------- PE table + zero stats ----------
__global__ void k_pe(float* __restrict__ pe, float* __restrict__ sums, float* __restrict__ sqs) {
  int idx = blockIdx.x * 256 + threadIdx.x;  // < 197*768 = 151296 exactly
  int s = idx / 768;
  int j = idx - s * 768;
  int jj = j & ~1;
  float ang = (float)s * expf((float)jj * (-9.210340371976184f / 768.0f));
  pe[idx] = (j & 1) ? cosf(ang) : sinf(ang);
  if (blockIdx.x == 0 && threadIdx.x < 128) {
    sums[threadIdx.x] = 0.f;
    sqs[threadIdx.x] = 0.f;
  }
}

// ---------- img + W_map fp32 -> bf16 (one pass; 2048 elems/block, 9696 blocks exact) ----------
__global__ void k_cvt(const float* __restrict__ img, const float* __restrict__ W,
                      unsigned short* __restrict__ imgbf, unsigned short* __restrict__ wbf) {
  size_t i = ((size_t)blockIdx.x * 256 + threadIdx.x) * 8;
  const float* src;
  unsigned short* dst;
  if (i < 19267584) { src = img + i; dst = imgbf + i; }
  else { size_t j = i - 19267584; src = W + j; dst = wbf + j; }
  const fx4* p = (const fx4*)src;
  *(ushort8*)dst = pack8(p[0], p[1]);
}

// ---------- Wq|Wk|Wv fp32 -> bf16, row-major [3][12][64][64] (72 blocks exact) ----------
__global__ void k_wcvt(const float* __restrict__ Wq, const float* __restrict__ Wk,
                       const float* __restrict__ Wv, unsigned short* __restrict__ wqkv) {
  int i = (blockIdx.x * 256 + threadIdx.x) * 8;  // < 147456
  const float* src = (i < 49152) ? (Wq + i) : (i < 98304 ? Wk + (i - 49152) : Wv + (i - 98304));
  const fx4* p = (const fx4*)src;
  *(ushort8*)(wqkv + i) = pack8(p[0], p[1]);
}

// ---------- tokens = patches @ W_map^T + b_map + PE; also LN partial stats ----------
__global__ __launch_bounds__(256) void k_tokens(
    const unsigned short* __restrict__ imgbf, const unsigned short* __restrict__ wbf,
    const float* __restrict__ bmap, const float* __restrict__ pe,
    float* __restrict__ out, float* __restrict__ sums, float* __restrict__ sqs) {
  __shared__ __align__(16) ushort8 Sf[16 * 64];  // blobs 0-7: A(128x32), 8-15: B(128x32)
  if (blockIdx.x >= 196) return;
  const int tid = threadIdx.x;
  const int m0 = blockIdx.x * 128;
  const int n0 = blockIdx.y * 128;
  const int lane = tid & 63;
  const int w = tid >> 6;
  const int quad = lane >> 4, l16 = lane & 15;
  const int m_off = (w & 1) * 64, n_off = (w >> 1) * 64;

  fx4 acc[4][4];
#pragma unroll
  for (int i = 0; i < 4; i++)
#pragma unroll
    for (int j = 0; j < 4; j++) acc[i][j] = (fx4){0.f, 0.f, 0.f, 0.f};

  const unsigned short* pA = imgbf + (size_t)(m0 + w * 16 + l16) * 768 + quad * 8;
  const unsigned short* pB = wbf + (size_t)(n0 + w * 16 + l16) * 768 + quad * 8;
  void* lA0 = (void*)&Sf[(w) * 64];
  void* lA1 = (void*)&Sf[(4 + w) * 64];
  void* lB0 = (void*)&Sf[(8 + w) * 64];
  void* lB1 = (void*)&Sf[(12 + w) * 64];

  for (int k0 = 0; k0 < 768; k0 += 32) {
    __syncthreads();
    gl2lds16(pA + k0, lA0);
    gl2lds16(pA + 64 * 768 + k0, lA1);
    gl2lds16(pB + k0, lB0);
    gl2lds16(pB + 64 * 768 + k0, lB1);
    __syncthreads();
    bf16x8 a[4], b[4];
#pragma unroll
    for (int mt = 0; mt < 4; mt++)
      a[mt] = __builtin_bit_cast(bf16x8, Sf[((w & 1) * 4 + mt) * 64 + lane]);
#pragma unroll
    for (int nt = 0; nt < 4; nt++)
      b[nt] = __builtin_bit_cast(bf16x8, Sf[(8 + (w >> 1) * 4 + nt) * 64 + lane]);
#pragma unroll
    for (int mt = 0; mt < 4; mt++)
#pragma unroll
      for (int nt = 0; nt < 4; nt++) acc[mt][nt] = MFMA16(a[mt], b[nt], acc[mt][nt]);
  }

  float s0 = 0.f, q0 = 0.f, s1 = 0.f, q1 = 0.f;
  const int b0 = m0 / 196;
#pragma unroll
  for (int mt = 0; mt < 4; mt++) {
#pragma unroll
    for (int nt = 0; nt < 4; nt++) {
      const int col = n0 + n_off + nt * 16 + l16;
      const float bc = bmap[col];
#pragma unroll
      for (int r = 0; r < 4; r++) {
        const int gm = m0 + m_off + mt * 16 + quad * 4 + r;
        const int bb = gm / 196;
        const int ss = gm - bb * 196 + 1;  // class token occupies s=0
        float val = acc[mt][nt][r] + bc + pe[ss * 768 + col];
        out[((size_t)bb * 197 + ss) * 768 + col] = val;
        if (bb == b0) { s0 += val; q0 += val * val; }
        else          { s1 += val; q1 += val * val; }
      }
    }
  }
  for (int off = 32; off > 0; off >>= 1) {
    s0 += __shfl_down(s0, off); q0 += __shfl_down(q0, off);
    s1 += __shfl_down(s1, off); q1 += __shfl_down(q1, off);
  }
  if (lane == 0) {
    atomicAdd(&sums[b0], s0);
    atomicAdd(&sqs[b0], q0);
    if (b0 + 1 < 128) { atomicAdd(&sums[b0 + 1], s1); atomicAdd(&sqs[b0 + 1], q1); }
  }
}

// ---------- class token row (s=0) + its stats ----------
__global__ __launch_bounds__(256) void k_cls(
    const float* __restrict__ ct, const float* __restrict__ pe,
    float* __restrict__ out, float* __restrict__ sums, float* __restrict__ sqs) {
  const int b = blockIdx.x, tid = threadIdx.x;
  float s = 0.f, q = 0.f;
#pragma unroll
  for (int it = 0; it < 3; it++) {
    int j = tid + it * 256;
    float v = ct[j] + pe[j];  // PE row 0
    out[(size_t)b * 197 * 768 + j] = v;
    s += v; q += v * v;
  }
  for (int off = 32; off > 0; off >>= 1) { s += __shfl_down(s, off); q += __shfl_down(q, off); }
  __shared__ float rs[4], rq[4];
  int w = tid >> 6;
  if ((tid & 63) == 0) { rs[w] = s; rq[w] = q; }
  __syncthreads();
  if (tid == 0) {
    atomicAdd(&sums[b], rs[0] + rs[1] + rs[2] + rs[3]);
    atomicAdd(&sqs[b], rq[0] + rq[1] + rq[2] + rq[3]);
  }
}

// ---------- finalize mean/rstd ----------
__global__ void k_fin(const float* __restrict__ sums, const float* __restrict__ sqs,
                      float* __restrict__ mr) {
  int i = threadIdx.x;  // 128
  const float inv = 1.0f / 151296.0f;
  float m = sums[i] * inv;
  float v = sqs[i] * inv - m * m;
  mr[2 * i] = m;
  mr[2 * i + 1] = rsqrtf(v + 1e-5f);
}

// ---------- fused LN + QKV projection + attention, per (b,h) ----------
// Phase A: Q^T/K^T = MFMA(W, X_ln) (C-layout col=m on l16); quad-redistribute to
//   B-frag layout -> qfr regs (per-wave query tiles) / Kf LDS blobs.
// Phase B: V = MFMA(X_ln, Wv) (col=e on l16); redistribute -> Vf LDS blobs.
// One barrier, then the verified attention phase (softmax mask + PV + RMW out).
__global__ __launch_bounds__(256, 2) void k_fused(
    const float* tok, const float* __restrict__ mr,
    const float* __restrict__ lnw, const float* __restrict__ lnb,
    const unsigned short* __restrict__ wqkv,
    const float* __restrict__ bq, const float* __restrict__ bk, const float* __restrict__ bv,
    float* out) {
  __shared__ __align__(16) ushort8 Kf[26 * 64];   // [nt][kk][lane] 26624 B
  __shared__ __align__(16) ushort8 Vf[28 * 64];   // [et][kk7][lane] 28672 B
  const int tid = threadIdx.x;
  const int bh = blockIdx.x;
  const int b = bh / 12;
  const int h = bh - b * 12;
  const int lane = tid & 63;
  const int w = tid >> 6;
  const int quad = lane >> 4;
  const int l16 = lane & 15;
  const int src0 = l16 + ((quad & 1) << 5);
  const int src1 = src0 + 16;
  const float mean = mr[2 * b], rstd = mr[2 * b + 1];
  const int hcol = h * 64;

  bf16x8 qfr[4][2];

  // ---- Phase A: Q (regs) + K (LDS) for tiles mt = w, w+4, w+8, w+12 ----
  {
    bf16x8 wq[4][2], wk[4][2];
    fx4 bqv[4], bkv[4];
#pragma unroll
    for (int et = 0; et < 4; et++) {
      const int ro = (et * 16 + l16) * 64 + quad * 8;
#pragma unroll
      for (int kk = 0; kk < 2; kk++) {
        wq[et][kk] = *(const bf16x8*)(wqkv + h * 4096 + ro + kk * 32);
        wk[et][kk] = *(const bf16x8*)(wqkv + 49152 + h * 4096 + ro + kk * 32);
      }
      bqv[et] = *(const fx4*)(bq + hcol + et * 16 + quad * 4);
      bkv[et] = *(const fx4*)(bk + hcol + et * 16 + quad * 4);
    }
#pragma unroll
    for (int mi = 0; mi < 4; mi++) {
      const int mt = w + mi * 4;
      if (mt < 13) {
        int ss = mt * 16 + l16;
        ss = (ss < 197) ? ss : 196;  // clamped rows only feed masked outputs
        bf16x8 xf[2];
#pragma unroll
        for (int kk = 0; kk < 2; kk++) {
          const int col = hcol + kk * 32 + quad * 8;
          const fx4* px = (const fx4*)(tok + (size_t)(b * 197 + ss) * 768 + col);
          const fx4* pw = (const fx4*)(lnw + (size_t)ss * 768 + col);
          const fx4* pb = (const fx4*)(lnb + (size_t)ss * 768 + col);
          fx4 y0 = (px[0] - mean) * rstd * pw[0] + pb[0];
          fx4 y1 = (px[1] - mean) * rstd * pw[1] + pb[1];
          xf[kk] = __builtin_bit_cast(bf16x8, pack8(y0, y1));
        }
        fx4 aq[4], ak[4];
#pragma unroll
        for (int et = 0; et < 4; et++) {
          aq[et] = (fx4){0.f, 0.f, 0.f, 0.f};
          ak[et] = (fx4){0.f, 0.f, 0.f, 0.f};
        }
#pragma unroll
        for (int kk = 0; kk < 2; kk++)
#pragma unroll
          for (int et = 0; et < 4; et++) {
            aq[et] = MFMA16(wq[et][kk], xf[kk], aq[et]);  // D[e][m], col=m=l16
            ak[et] = MFMA16(wk[et][kk], xf[kk], ak[et]);
          }
        uint2v qp[4], kp[4];
#pragma unroll
        for (int et = 0; et < 4; et++) {
          qp[et] = pack2(aq[et] + bqv[et]);
          kp[et] = pack2(ak[et] + bkv[et]);
        }
#pragma unroll
        for (int kk = 0; kk < 2; kk++) {
          qfr[mi][kk] = xfrm(qp[2 * kk], qp[2 * kk + 1], quad, src0, src1);
          bf16x8 kfrag = xfrm(kp[2 * kk], kp[2 * kk + 1], quad, src0, src1);
          Kf[(mt * 2 + kk) * 64 + lane] = __builtin_bit_cast(ushort8, kfrag);
        }
      }
    }
  }

  // ---- Phase B: V^T fragments (LDS) for t-tile pairs jp = w, w+4 ----
  {
    bf16x8 wv[4][2];
    float bvs[4];
#pragma unroll
    for (int et = 0; et < 4; et++) {
      const int ro = (et * 16 + l16) * 64 + quad * 8;
#pragma unroll
      for (int kk = 0; kk < 2; kk++)
        wv[et][kk] = *(const bf16x8*)(wqkv + 98304 + h * 4096 + ro + kk * 32);
      bvs[et] = bv[hcol + et * 16 + l16];
    }
#pragma unroll
    for (int ji = 0; ji < 2; ji++) {
      const int jp = w + ji * 4;
      if (jp < 7) {
        fx4 av[2][4];
#pragma unroll
        for (int s2 = 0; s2 < 2; s2++)
#pragma unroll
          for (int et = 0; et < 4; et++) av[s2][et] = (fx4){0.f, 0.f, 0.f, 0.f};
#pragma unroll
        for (int s2 = 0; s2 < 2; s2++) {
          const int tt = 2 * jp + s2;
          if (tt < 13) {  // tile 13 (t>=208) stays zero; masked by P anyway
            int ss = tt * 16 + l16;
            ss = (ss < 197) ? ss : 196;
            bf16x8 xf[2];
#pragma unroll
            for (int kk = 0; kk < 2; kk++) {
              const int col = hcol + kk * 32 + quad * 8;
              const fx4* px = (const fx4*)(tok + (size_t)(b * 197 + ss) * 768 + col);
              const fx4* pw = (const fx4*)(lnw + (size_t)ss * 768 + col);
              const fx4* pb = (const fx4*)(lnb + (size_t)ss * 768 + col);
              fx4 y0 = (px[0] - mean) * rstd * pw[0] + pb[0];
              fx4 y1 = (px[1] - mean) * rstd * pw[1] + pb[1];
              xf[kk] = __builtin_bit_cast(bf16x8, pack8(y0, y1));
            }
#pragma unroll
            for (int kk = 0; kk < 2; kk++)
#pragma unroll
              for (int et = 0; et < 4; et++)
                av[s2][et] = MFMA16(xf[kk], wv[et][kk], av[s2][et]);  // D[t][e], col=e=l16
          }
        }
#pragma unroll
        for (int et = 0; et < 4; et++) {
          fx4 bb = (fx4){bvs[et], bvs[et], bvs[et], bvs[et]};
          uint2v v0 = pack2(av[0][et] + bb);
          uint2v v1 = pack2(av[1][et] + bb);
          bf16x8 vfrag = xfrm(v0, v1, quad, src0, src1);
          Vf[(et * 7 + jp) * 64 + lane] = __builtin_bit_cast(ushort8, vfrag);
        }
      }
    }
  }
  __syncthreads();

  // ---- attention (unchanged structure; qf from registers) ----
#pragma unroll
  for (int mi = 0; mi < 4; mi++) {
    const int mt = w + mi * 4;
    if (mt < 13) {
      fx4 sacc[13];
#pragma unroll
      for (int nt = 0; nt < 13; nt++) sacc[nt] = (fx4){0.f, 0.f, 0.f, 0.f};
#pragma unroll
      for (int kk = 0; kk < 2; kk++) {
        bf16x8 qf = qfr[mi][kk];
#pragma unroll
        for (int nt = 0; nt < 13; nt++) {
          bf16x8 kf = __builtin_bit_cast(bf16x8, Kf[(nt * 2 + kk) * 64 + lane]);
          sacc[nt] = MFMA16(kf, qf, sacc[nt]);  // D[t][m]: col=m=l16, row=t
        }
      }
      // softmax over t (no max-sub: |s|*0.125 small by construction)
      float sm = 0.f;
      uint2v pk[13];
#pragma unroll
      for (int nt = 0; nt < 13; nt++) {
        float p[4];
#pragma unroll
        for (int r = 0; r < 4; r++) {
          const bool valid = (nt < 12) | (quad * 4 + r < 5);  // t < 197
          p[r] = valid ? __expf(sacc[nt][r] * 0.125f) : 0.f;
          sm += p[r];
        }
        pk[nt][0] = (unsigned int)f2bf(p[0]) | ((unsigned int)f2bf(p[1]) << 16);
        pk[nt][1] = (unsigned int)f2bf(p[2]) | ((unsigned int)f2bf(p[3]) << 16);
      }
      sm += __shfl_xor(sm, 16);
      sm += __shfl_xor(sm, 32);
      const float inv = 1.0f / sm;

      fx4 oacc[4];
#pragma unroll
      for (int et = 0; et < 4; et++) oacc[et] = (fx4){0.f, 0.f, 0.f, 0.f};
#pragma unroll
      for (int kk = 0; kk < 7; kk++) {
        uint4v pf;
        if (kk < 6) {
          const int nA = 2 * kk, nB = 2 * kk + 1;
#pragma unroll
          for (int d = 0; d < 2; d++) {
            int a0 = __shfl((int)pk[nA][d], src0, 64);
            int b0 = __shfl((int)pk[nB][d], src0, 64);
            pf[d] = (unsigned int)((quad < 2) ? a0 : b0);
            int a1 = __shfl((int)pk[nA][d], src1, 64);
            int b1 = __shfl((int)pk[nB][d], src1, 64);
            pf[2 + d] = (unsigned int)((quad < 2) ? a1 : b1);
          }
        } else {
#pragma unroll
          for (int d = 0; d < 2; d++) {
            int a0 = __shfl((int)pk[12][d], src0, 64);
            pf[d] = (quad < 2) ? (unsigned int)a0 : 0u;
            int a1 = __shfl((int)pk[12][d], src1, 64);
            pf[2 + d] = (quad < 2) ? (unsigned int)a1 : 0u;
          }
        }
        bf16x8 pfrag = __builtin_bit_cast(bf16x8, pf);
#pragma unroll
        for (int et = 0; et < 4; et++) {
          bf16x8 vf = __builtin_bit_cast(bf16x8, Vf[(et * 7 + kk) * 64 + lane]);
          oacc[et] = MFMA16(vf, pfrag, oacc[et]);  // D[e][m]: col=m=l16, row=e
        }
      }
      const int sg = mt * 16 + l16;
      if (sg < 197) {
        float* op = out + ((size_t)b * 197 + sg) * 768 + hcol + quad * 4;
#pragma unroll
        for (int et = 0; et < 4; et++) {
          fx4 cur = *(const fx4*)(op + et * 16);
          cur += oacc[et] * inv;
          *(fx4*)(op + et * 16) = cur;
        }
      }
    }
  }
}

extern "C" void kernel_launch(void* const* d_in, const int* in_sizes, int n_in,
                              void* d_out, int out_size, void* d_ws, size_t ws_size,
                              hipStream_t stream) {
  (void)in_sizes; (void)n_in; (void)out_size; (void)ws_size;
  const float* img  = (const float*)d_in[0];
  const float* Wmap = (const float*)d_in[1];
  const float* bmap = (const float*)d_in[2];
  const float* ct   = (const float*)d_in[3];
  const float* lnw  = (const float*)d_in[4];
  const float* lnb  = (const float*)d_in[5];
  const float* Wq   = (const float*)d_in[6];
  const float* bq   = (const float*)d_in[7];
  const float* Wk   = (const float*)d_in[8];
  const float* bk   = (const float*)d_in[9];
  const float* Wv   = (const float*)d_in[10];
  const float* bv   = (const float*)d_in[11];
  float* out = (float*)d_out;

  // ws layout (~41 MiB): pe | sums | sqs | mean_rstd | W_bf16 | img_bf16 | Wqkv_bf16
  float* pe   = (float*)d_ws;                 // 151296 f
  float* sums = pe + 151296;                  // 128 f
  float* sqs  = sums + 128;                   // 128 f
  float* mr   = sqs + 128;                    // 256 f
  unsigned short* wbf   = (unsigned short*)(mr + 256);   // 589824 u16
  unsigned short* imgbf = wbf + 589824;                  // 19267584 u16
  unsigned short* wqkv  = imgbf + (size_t)19267584;      // 147456 u16

  k_pe<<<591, 256, 0, stream>>>(pe, sums, sqs);
  k_cvt<<<9696, 256, 0, stream>>>(img, Wmap, imgbf, wbf);
  k_wcvt<<<72, 256, 0, stream>>>(Wq, Wk, Wv, wqkv);
  k_tokens<<<dim3(200, 6), 256, 0, stream>>>(imgbf, wbf, bmap, pe, out, sums, sqs);
  k_cls<<<128, 256, 0, stream>>>(ct, pe, out, sums, sqs);
  k_fin<<<1, 128, 0, stream>>>(sums, sqs, mr);
  k_fused<<<1536, 256, 0, stream>>>(out, mr, lnw, lnb, wqkv, bq, bk, bv, out);
}